// Round 2
// 725.373 us; speedup vs baseline: 1.0195x; 1.0195x over previous
//
#include <hip/hip_runtime.h>
#include <hip/hip_bf16.h>
#include <cstdint>
#include <cstddef>

// Problem constants
#define B_    8192
#define IN_   4096
#define OUT_  4096
#define F_    16
#define FS_   256
#define COMP_ 1024
#define KBIG  (IN_ + COMP_)   // 5120 fused-K

typedef unsigned short ushort_t;
typedef __attribute__((ext_vector_type(8))) short short8;   // 8 bf16 (4 VGPRs)
typedef __attribute__((ext_vector_type(4))) float f32x4;    // MFMA acc

// fp32 -> bf16 round-to-nearest-even (finite inputs only)
__device__ __forceinline__ ushort_t f2b(float f) {
  unsigned u = __float_as_uint(f);
  u += 0x7fffu + ((u >> 16) & 1u);
  return (ushort_t)(u >> 16);
}

// async global->LDS, 16B per lane; lds dest = wave-uniform base + lane*16
__device__ __forceinline__ void gll16(const void* gp, void* lp) {
  __builtin_amdgcn_global_load_lds(
      (const __attribute__((address_space(1))) unsigned int*)gp,
      (__attribute__((address_space(3))) unsigned int*)lp, 16, 0, 0);
}

// ---------------------------------------------------------------------------
// K1: per-row selector scores -> softmax -> write y (gated) into A_big cols
// [0,4096) and m = x - y into Mbuf, both bf16. One row per 256-thread block.
// ---------------------------------------------------------------------------
__global__ void __launch_bounds__(256) gate_kernel(
    const float* __restrict__ x, const float* __restrict__ sel,
    ushort_t* __restrict__ Abig, ushort_t* __restrict__ Mbuf) {
  const int row = blockIdx.x;
  const int t = threadIdx.x;            // 0..255, 16 elems each
  const float* xr = x + (size_t)row * IN_ + t * 16;
  float4 xv0 = ((const float4*)xr)[0];
  float4 xv1 = ((const float4*)xr)[1];
  float4 xv2 = ((const float4*)xr)[2];
  float4 xv3 = ((const float4*)xr)[3];

  const int f = t >> 4;                 // fragment of this thread
  const int sub = t & 15;
  const float* sp = sel + f * FS_ + sub * 16;
  float4 s0 = ((const float4*)sp)[0];
  float4 s1 = ((const float4*)sp)[1];
  float4 s2 = ((const float4*)sp)[2];
  float4 s3 = ((const float4*)sp)[3];

  float dot = xv0.x * s0.x + xv0.y * s0.y + xv0.z * s0.z + xv0.w * s0.w
            + xv1.x * s1.x + xv1.y * s1.y + xv1.z * s1.z + xv1.w * s1.w
            + xv2.x * s2.x + xv2.y * s2.y + xv2.z * s2.z + xv2.w * s2.w
            + xv3.x * s3.x + xv3.y * s3.y + xv3.z * s3.z + xv3.w * s3.w;

  // reduce across the 16 lanes of this fragment (lane groups are 16-aligned)
  #pragma unroll
  for (int off = 8; off; off >>= 1) dot += __shfl_xor(dot, off, 64);

  __shared__ float sc[F_];
  if (sub == 0) sc[f] = dot;
  __syncthreads();

  float mx = sc[0];
  #pragma unroll
  for (int i = 1; i < F_; ++i) mx = fmaxf(mx, sc[i]);
  float sum = 0.f;
  #pragma unroll
  for (int i = 0; i < F_; ++i) sum += __expf(sc[i] - mx);
  const float p = __expf(sc[f] - mx) / sum;

  float xs[16] = {xv0.x, xv0.y, xv0.z, xv0.w, xv1.x, xv1.y, xv1.z, xv1.w,
                  xv2.x, xv2.y, xv2.z, xv2.w, xv3.x, xv3.y, xv3.z, xv3.w};
  union { ushort_t u[8]; uint4 v; } a0, a1, m0, m1;
  #pragma unroll
  for (int j = 0; j < 8; ++j) {
    float y0 = xs[j] * p;
    float y1 = xs[8 + j] * p;
    a0.u[j] = f2b(y0);
    a1.u[j] = f2b(y1);
    m0.u[j] = f2b(xs[j] - y0);
    m1.u[j] = f2b(xs[8 + j] - y1);
  }
  ushort_t* ap = Abig + (size_t)row * KBIG + t * 16;
  *(uint4*)ap = a0.v;
  *(uint4*)(ap + 8) = a1.v;
  ushort_t* mp = Mbuf + (size_t)row * IN_ + t * 16;
  *(uint4*)mp = m0.v;
  *(uint4*)(mp + 8) = m1.v;
}

// ---------------------------------------------------------------------------
// K2a: expert_weights [IN][OUT] fp32 -> B_big[o][k] bf16 (transposed).
// ---------------------------------------------------------------------------
__global__ void __launch_bounds__(256) conv_expertT(
    const float* __restrict__ We, ushort_t* __restrict__ Bbig) {
  __shared__ float tile[64][65];
  const int k0 = blockIdx.x * 64;
  const int o0 = blockIdx.y * 64;
  const int t = threadIdx.x;
  const int kr = t >> 4;      // 0..15
  const int oq = t & 15;      // 0..15, float4 column
  #pragma unroll
  for (int rr = 0; rr < 4; ++rr) {
    int k = rr * 16 + kr;
    float4 v = *(const float4*)(We + (size_t)(k0 + k) * OUT_ + o0 + oq * 4);
    tile[k][oq * 4 + 0] = v.x;
    tile[k][oq * 4 + 1] = v.y;
    tile[k][oq * 4 + 2] = v.z;
    tile[k][oq * 4 + 3] = v.w;
  }
  __syncthreads();
  const int kc = t & 7;       // 16B k-chunk
  #pragma unroll
  for (int rr = 0; rr < 2; ++rr) {
    int o = rr * 32 + (t >> 3);
    union { ushort_t u[8]; uint4 v; } w;
    #pragma unroll
    for (int j = 0; j < 8; ++j) w.u[j] = f2b(tile[kc * 8 + j][o]);
    *(uint4*)(Bbig + (size_t)(o0 + o) * KBIG + k0 + kc * 8) = w.v;
  }
}

// K2b: W_net [OUT][COMP] fp32 -> B_big[o][4096 + c] bf16, 8 elems/thread
__global__ void __launch_bounds__(256) conv_net(
    const float* __restrict__ Wnet, ushort_t* __restrict__ Bbig) {
  int tid = blockIdx.x * 256 + threadIdx.x;     // OUT_*COMP_/8 threads
  int base = tid * 8;
  int o = base >> 10;
  int c = base & (COMP_ - 1);
  float4 v0 = ((const float4*)(Wnet + base))[0];
  float4 v1 = ((const float4*)(Wnet + base))[1];
  union { ushort_t u[8]; uint4 v; } w;
  w.u[0] = f2b(v0.x); w.u[1] = f2b(v0.y); w.u[2] = f2b(v0.z); w.u[3] = f2b(v0.w);
  w.u[4] = f2b(v1.x); w.u[5] = f2b(v1.y); w.u[6] = f2b(v1.z); w.u[7] = f2b(v1.w);
  *(uint4*)(Bbig + (size_t)o * KBIG + IN_ + c) = w.v;
}

// K2c: W_comp [COMP][IN] fp32 -> bf16 flat, 8 elems/thread
__global__ void __launch_bounds__(256) conv_comp(
    const float* __restrict__ Wc, ushort_t* __restrict__ Wcb) {
  int tid = blockIdx.x * 256 + threadIdx.x;     // COMP_*IN_/8 threads
  int base = tid * 8;
  float4 v0 = ((const float4*)(Wc + base))[0];
  float4 v1 = ((const float4*)(Wc + base))[1];
  union { ushort_t u[8]; uint4 v; } w;
  w.u[0] = f2b(v0.x); w.u[1] = f2b(v0.y); w.u[2] = f2b(v0.z); w.u[3] = f2b(v0.w);
  w.u[4] = f2b(v1.x); w.u[5] = f2b(v1.y); w.u[6] = f2b(v1.z); w.u[7] = f2b(v1.w);
  *(uint4*)(Wcb + base) = w.v;
}

// split-K reduce for the small GEMM: compressed = p0 + p1 -> bf16 into
// A_big cols [4096,5120).
__global__ void __launch_bounds__(256) reduce_split(
    const float* __restrict__ p0, const float* __restrict__ p1,
    ushort_t* __restrict__ Abig) {
  int tid = blockIdx.x * 256 + threadIdx.x;     // B_*COMP_/4 threads
  float4 a = ((const float4*)p0)[tid];
  float4 b = ((const float4*)p1)[tid];
  int row = tid >> 8;                           // 256 float4 per row
  int c4 = tid & 255;
  union { ushort_t u[4]; uint2 v; } w;
  w.u[0] = f2b(a.x + b.x);
  w.u[1] = f2b(a.y + b.y);
  w.u[2] = f2b(a.z + b.z);
  w.u[3] = f2b(a.w + b.w);
  *(uint2*)(Abig + (size_t)row * KBIG + IN_ + c4 * 4) = w.v;
}

// ---------------------------------------------------------------------------
// R6 GEMM (= R5 + rule-18 sched_barrier hardening): 256x256 tile, BK=64,
// 512 threads = 8 waves (2M x 4N), 8-phase schedule with counted vmcnt
// (T3+T4), setprio around MFMA clusters (T5), XCD-bijective block swizzle
// (T1). LDS 128 KiB: per operand 2 dbuf x [256 rows][64 k] bf16, halves
// staged separately. XOR-chunk swizzle: LDS slot s of row holds global
// k-chunk s^(row&7) (pre-swizzled global source, linear LDS dest for
// global_load_lds; reads XOR the slot back) -> bank-conflict-free.
//
// Per-wave output: 128x64 (M_rep=8, N_rep=4), acc = f32x4[8][4] = 128 VGPR.
// Phase p of tile t (one C-quadrant x K=64 = 16 MFMA each):
//   p0: ds_read A(m0-3)x2ks + B(n0-1)x2ks (12xb128); stage A-half0(t+1)
//   p1: ds_read B(n2-3)x2ks (4);                     stage A-half1(t+1)
//   p2: ds_read A(m4-7)x2ks (8);                     stage B-half0(t+2)
//   p3: (no reads);                                  stage B-half1(t+2)
//   each phase: barrier; lgkmcnt(0); sched_barrier(0); setprio(1); 16 MFMA;
//               setprio(0); barrier
//   tile boundary (end p3): vmcnt(4) -- B(t+2)'s 4 loads stay in flight
//                           across the barrier; never drained to 0 mid-loop.
// Slot safety: A(t+1) -> other dbuf (free). B(t+2) -> this tile's B slots,
// last ds_read in p1, staged after p1's closing barrier (p2/p3). Boundary
// vmcnt(4) guarantees A(t+1) + all older stages landed before any wave
// reads tile t+1.
// ---------------------------------------------------------------------------
template <bool BF16_OUT>
__global__ void __launch_bounds__(512, 2) gemm256(
    const ushort_t* __restrict__ A, int lda,
    const ushort_t* __restrict__ Bt, int ldb,
    int KS, void* __restrict__ Cp, int ldc, int num_pid_n,
    int num_pid, size_t coff) {
  __shared__ __align__(16) ushort_t As[2 * 256 * 64];   // 64 KiB
  __shared__ __align__(16) ushort_t Bs[2 * 256 * 64];   // 64 KiB
  const int t = threadIdx.x;
  const int wave = t >> 6;
  const int lane = t & 63;

  // split-K decomposition
  const int s = blockIdx.x / num_pid;
  int rem_all = blockIdx.x - s * num_pid;
  A += (size_t)s * KS;
  Bt += (size_t)s * KS;

  // XCD-aware bijective swizzle (num_pid % 8 == 0 for both call sites)
  rem_all = (rem_all & 7) * (num_pid >> 3) + (rem_all >> 3);

  // grouped supertile: 16 m-tiles per group, n sweeps within group
  const int pids_per_group = num_pid_n << 4;
  const int group_id = rem_all / pids_per_group;
  const int rem = rem_all - group_id * pids_per_group;
  const int pid_m = (group_id << 4) + (rem & 15);
  const int pid_n = rem >> 4;

  // wave tile position: 2 (M) x 4 (N)
  const int wr = (wave >> 2) * 128;   // 0 or 128
  const int wc = (wave & 3) * 64;     // 0,64,128,192

  // ---- staging addressing (global -> LDS, pre-swizzled source) ----
  const int lr = lane >> 3;                 // row within 8-row group
  const int gch = (lane & 7) ^ lr;          // pre-swizzled global k-chunk
  const ushort_t* gA = A + (size_t)(pid_m * 256 + wave * 8 + lr) * lda + gch * 8;
  const ushort_t* gB = Bt + (size_t)(pid_n * 256 + wave * 8 + lr) * ldb + gch * 8;
  const size_t a64 = (size_t)64 * lda;      // 64-row stride
  const size_t b64 = (size_t)64 * ldb;
  ushort_t* lA = As + wave * 512;           // wave-uniform LDS base
  ushort_t* lB = Bs + wave * 512;

  // stage one 128-row half (H in {0,1}) of K-tile KT into dbuf BF:
  // 2 x gll16 per thread; lds rows H*128 + {0,64} + wave*8 + (lane>>3)
  #define STAGE_A(BF, H, KT) do {                                          \
    const ushort_t* g_ = gA + (size_t)(KT) * 64 + (size_t)(2 * (H)) * a64; \
    ushort_t* d_ = lA + (BF) * 16384 + (H) * 8192;                         \
    gll16(g_, d_);                                                         \
    gll16(g_ + a64, d_ + 4096); } while (0)
  #define STAGE_B(BF, H, KT) do {                                          \
    const ushort_t* g_ = gB + (size_t)(KT) * 64 + (size_t)(2 * (H)) * b64; \
    ushort_t* d_ = lB + (BF) * 16384 + (H) * 8192;                         \
    gll16(g_, d_);                                                         \
    gll16(g_ + b64, d_ + 4096); } while (0)

  // ---- fragment read addressing (LDS -> VGPR) ----
  const int r = lane & 15;
  const int q = lane >> 4;
  const int sw = r & 7;
  const int sl0 = (q ^ sw) * 8;             // slot for k-chunk q      (ks=0)
  const int sl1 = ((q + 4) ^ sw) * 8;       // slot for k-chunk 4+q    (ks=1)
  const ushort_t* aRd = As + (wr >> 7) * 8192 + r * 64;
  const ushort_t* bRd = Bs + (wc >> 7) * 8192 + (wc & 64) * 64 + r * 64;

  const int nt = KS >> 6;

  f32x4 acc[8][4] = {};
  short8 a[4][2], b[4][2];

  #define MFMA_PH(MB, NB) do {                                            \
    __builtin_amdgcn_s_setprio(1);                                        \
    _Pragma("unroll")                                                     \
    for (int mi = 0; mi < 4; ++mi) {                                      \
      _Pragma("unroll")                                                   \
      for (int nj = 0; nj < 2; ++nj) {                                    \
        _Pragma("unroll")                                                 \
        for (int ks = 0; ks < 2; ++ks)                                    \
          acc[(MB) + mi][(NB) + nj] =                                     \
              __builtin_amdgcn_mfma_f32_16x16x32_bf16(                    \
                  a[mi][ks], b[(NB) + nj][ks], acc[(MB) + mi][(NB) + nj], \
                  0, 0, 0);                                               \
      }                                                                   \
    }                                                                     \
    __builtin_amdgcn_s_setprio(0); } while (0)

  #define WAIT_LGKM0() do {                                               \
    asm volatile("s_waitcnt lgkmcnt(0)" ::: "memory");                    \
    __builtin_amdgcn_sched_barrier(0); } while (0)

  // ---- prologue: tile 0 (both operands) + B(1); counted wait ----
  STAGE_A(0, 0, 0); STAGE_A(0, 1, 0);
  STAGE_B(0, 0, 0); STAGE_B(0, 1, 0);
  if (nt > 1) {
    STAGE_B(1, 0, 1); STAGE_B(1, 1, 1);
    asm volatile("s_waitcnt vmcnt(4)" ::: "memory");  // tile 0 landed
  } else {
    asm volatile("s_waitcnt vmcnt(0)" ::: "memory");
  }
  __builtin_amdgcn_sched_barrier(0);
  __builtin_amdgcn_s_barrier();

  for (int kt = 0; kt < nt; ++kt) {
    const int bf = kt & 1;
    const int nb = bf ^ 1;
    const ushort_t* aB = aRd + bf * 16384;
    const ushort_t* bB = bRd + bf * 16384;
    const bool p1ok = kt + 1 < nt;
    const bool p2ok = kt + 2 < nt;

    // ---- phase 0: A(m0-3), B(n0-1); stage A-half0(kt+1) ----
    #pragma unroll
    for (int mi = 0; mi < 4; ++mi) {
      a[mi][0] = *(const short8*)(aB + mi * 1024 + sl0);
      a[mi][1] = *(const short8*)(aB + mi * 1024 + sl1);
    }
    #pragma unroll
    for (int nj = 0; nj < 2; ++nj) {
      b[nj][0] = *(const short8*)(bB + nj * 1024 + sl0);
      b[nj][1] = *(const short8*)(bB + nj * 1024 + sl1);
    }
    if (p1ok) STAGE_A(nb, 0, kt + 1);
    __builtin_amdgcn_s_barrier();
    WAIT_LGKM0();
    MFMA_PH(0, 0);
    __builtin_amdgcn_s_barrier();

    // ---- phase 1: B(n2-3); stage A-half1(kt+1) ----
    #pragma unroll
    for (int nj = 2; nj < 4; ++nj) {
      b[nj][0] = *(const short8*)(bB + nj * 1024 + sl0);
      b[nj][1] = *(const short8*)(bB + nj * 1024 + sl1);
    }
    if (p1ok) STAGE_A(nb, 1, kt + 1);
    __builtin_amdgcn_s_barrier();
    WAIT_LGKM0();
    MFMA_PH(0, 2);
    __builtin_amdgcn_s_barrier();

    // ---- phase 2: A(m4-7); stage B-half0(kt+2) into this dbuf ----
    #pragma unroll
    for (int mi = 0; mi < 4; ++mi) {
      a[mi][0] = *(const short8*)(aB + (mi + 4) * 1024 + sl0);
      a[mi][1] = *(const short8*)(aB + (mi + 4) * 1024 + sl1);
    }
    if (p2ok) STAGE_B(bf, 0, kt + 2);
    __builtin_amdgcn_s_barrier();
    WAIT_LGKM0();
    MFMA_PH(4, 0);
    __builtin_amdgcn_s_barrier();

    // ---- phase 3: no reads; stage B-half1(kt+2); boundary vmcnt ----
    if (p2ok) STAGE_B(bf, 1, kt + 2);
    __builtin_amdgcn_s_barrier();
    MFMA_PH(4, 2);
    if (p2ok) asm volatile("s_waitcnt vmcnt(4)" ::: "memory");
    else      asm volatile("s_waitcnt vmcnt(0)" ::: "memory");
    __builtin_amdgcn_sched_barrier(0);
    __builtin_amdgcn_s_barrier();
  }

  // ---- epilogue: C/D layout col = lane&15, row = (lane>>4)*4 + reg ----
  const int row0 = pid_m * 256 + wr + q * 4;
  const int col0 = pid_n * 256 + wc + r;
  #pragma unroll
  for (int mi = 0; mi < 8; ++mi) {
    #pragma unroll
    for (int ni = 0; ni < 4; ++ni) {
      const int row = row0 + mi * 16;
      const int col = col0 + ni * 16;
      #pragma unroll
      for (int rr = 0; rr < 4; ++rr) {
        float v = acc[mi][ni][rr];
        if (BF16_OUT)
          ((ushort_t*)Cp)[(size_t)(row + rr) * ldc + col + s * coff] = f2b(v);
        else
          ((float*)Cp)[(size_t)(row + rr) * ldc + col + s * coff] = v;
      }
    }
  }
  #undef STAGE_A
  #undef STAGE_B
  #undef MFMA_PH
  #undef WAIT_LGKM0
}

// ---------------------------------------------------------------------------
extern "C" void kernel_launch(void* const* d_in, const int* in_sizes, int n_in,
                              void* d_out, int out_size, void* d_ws, size_t ws_size,
                              hipStream_t stream) {
  const float* x     = (const float*)d_in[0];
  const float* sel   = (const float*)d_in[1];
  const float* We    = (const float*)d_in[2];   // [F,FS,OUT] == [IN][OUT]
  const float* Wcomp = (const float*)d_in[3];   // [COMP][IN]
  const float* Wnet  = (const float*)d_in[4];   // [OUT][COMP]
  float* out = (float*)d_out;

  // workspace layout (bytes): A_big | Mbuf | B_big | Wcb
  char* ws = (char*)d_ws;
  const size_t szAbig = (size_t)B_ * KBIG * 2;     // 83,886,080
  const size_t szMbuf = (size_t)B_ * IN_ * 2;      // 67,108,864
  const size_t szBbig = (size_t)OUT_ * KBIG * 2;   // 41,943,040
  ushort_t* Abig = (ushort_t*)ws;
  ushort_t* Mbuf = (ushort_t*)(ws + szAbig);
  ushort_t* Bbig = (ushort_t*)(ws + szAbig + szMbuf);
  ushort_t* Wcb  = (ushort_t*)(ws + szAbig + szMbuf + szBbig);

  // split-K partials for the small GEMM live in d_out (overwritten by the
  // big GEMM at the end) — 2 x 8192x1024 fp32 = 67 MB of the 134 MB buffer.
  float* part0 = out;
  float* part1 = out + (size_t)B_ * COMP_;

  // 1) gating: scores/softmax -> y (A_big cols 0..4095) and m (Mbuf)
  gate_kernel<<<B_, 256, 0, stream>>>(x, sel, Abig, Mbuf);

  // 2) weight conversion (independent of 1)
  conv_expertT<<<dim3(IN_ / 64, OUT_ / 64), 256, 0, stream>>>(We, Bbig);
  conv_net<<<(OUT_ * COMP_) / (256 * 8), 256, 0, stream>>>(Wnet, Bbig);
  conv_comp<<<(COMP_ * IN_) / (256 * 8), 256, 0, stream>>>(Wcomp, Wcb);

  // 3) compressed = m @ W_comp^T, split-K=2 (grid 256 -> 1 blk/CU),
  //    fp32 partials into d_out, then reduce -> bf16 A_big cols 4096..5119
  gemm256<false><<<2 * (B_ / 256) * (COMP_ / 256), 512, 0, stream>>>(
      Mbuf, IN_, Wcb, IN_, IN_ / 2, (void*)part0, COMP_, COMP_ / 256,
      (B_ / 256) * (COMP_ / 256), (size_t)B_ * COMP_);
  reduce_split<<<(B_ * COMP_) / (256 * 4), 256, 0, stream>>>(part0, part1, Abig);

  // 4) out = [y|compressed] @ [We^T|Wnet]^T  (fused expert + net GEMM)
  gemm256<false><<<(B_ / 256) * (OUT_ / 256), 512, 0, stream>>>(
      Abig, KBIG, Bbig, KBIG, KBIG, (void*)out, OUT_, OUT_ / 256,
      (B_ / 256) * (OUT_ / 256), 0);
}